// Round 7
// baseline (3534.970 us; speedup 1.0000x reference)
//
#include <hip/hip_runtime.h>

typedef _Float16 f16x8 __attribute__((ext_vector_type(8)));
typedef float f32x4 __attribute__((ext_vector_type(4)));

constexpr int D = 256;
constexpr int NUTT = 64;
constexpr int L = 512;
constexpr int G = 768;           // 3*D

// LDS-only barrier: orders ds_* ops across the workgroup WITHOUT draining
// vmcnt — global prefetch loads / wo stores stay in flight across steps.
__device__ __forceinline__ void lds_barrier() {
  asm volatile("s_waitcnt lgkmcnt(0)\n\ts_barrier" ::: "memory");
}

__device__ __forceinline__ float sigm(float x) {
  return 1.0f / (1.0f + __expf(-x));
}
// tanh(x) = 1 - 2/(1+e^{2x}) : 5 instr, saturates correctly at +/-inf
__device__ __forceinline__ float tanh_f(float x) {
  float e = __expf(2.0f * x);
  return 1.0f - 2.0f / (1.0f + e);
}

// ---------------------------------------------------------------------------
// Kernel B: gx[m][g] = embed[tokens[m]][:] . Wih[g][:] + bih[g] (+bhh[g] for
// the r/z gates g<512 — folded here so the scan kernel saves work).
// ---------------------------------------------------------------------------
__global__ __launch_bounds__(256) void gx_gemm(
    const int* __restrict__ tokens, const float* __restrict__ embed,
    const float* __restrict__ Wih, const float* __restrict__ bih,
    const float* __restrict__ bhh, float* __restrict__ gx) {
  __shared__ float As[64][33];
  __shared__ float Bs[32][129];
  __shared__ int toks[64];

  const int tid = threadIdx.x;
  const int m0 = blockIdx.x * 64;
  const int n0 = blockIdx.y * 128;
  if (tid < 64) toks[tid] = tokens[m0 + tid];
  __syncthreads();

  const int ty = tid >> 4;   // 0..15 : row group (4 rows each)
  const int tx = tid & 15;   // 0..15 : col base (cols tx + 16*cc)
  float acc[4][8] = {};

  for (int k0 = 0; k0 < 256; k0 += 32) {
    {
      const int i = tid >> 2;            // 0..63
      const int kq = (tid & 3) * 4;      // 0,4,8,12
      const float* src = embed + (size_t)toks[i] * D + k0;
      float4 v0 = *(const float4*)(src + kq);
      float4 v1 = *(const float4*)(src + kq + 16);
      As[i][kq + 0] = v0.x; As[i][kq + 1] = v0.y;
      As[i][kq + 2] = v0.z; As[i][kq + 3] = v0.w;
      As[i][kq + 16] = v1.x; As[i][kq + 17] = v1.y;
      As[i][kq + 18] = v1.z; As[i][kq + 19] = v1.w;
    }
    {
      const int goff = tid >> 3;         // 0..31
      const int kq = (tid & 7) * 4;      // 0..28
      for (int gp = 0; gp < 128; gp += 32) {
        const float* src = Wih + (size_t)(n0 + goff + gp) * D + k0 + kq;
        float4 v = *(const float4*)src;
        Bs[kq + 0][goff + gp] = v.x;
        Bs[kq + 1][goff + gp] = v.y;
        Bs[kq + 2][goff + gp] = v.z;
        Bs[kq + 3][goff + gp] = v.w;
      }
    }
    __syncthreads();
    const int r0 = ty * 4;
#pragma unroll 4
    for (int k = 0; k < 32; ++k) {
      float a0 = As[r0 + 0][k], a1 = As[r0 + 1][k];
      float a2 = As[r0 + 2][k], a3 = As[r0 + 3][k];
#pragma unroll
      for (int cc = 0; cc < 8; ++cc) {
        float bv = Bs[k][tx + 16 * cc];
        acc[0][cc] = fmaf(a0, bv, acc[0][cc]);
        acc[1][cc] = fmaf(a1, bv, acc[1][cc]);
        acc[2][cc] = fmaf(a2, bv, acc[2][cc]);
        acc[3][cc] = fmaf(a3, bv, acc[3][cc]);
      }
    }
    __syncthreads();
  }
#pragma unroll
  for (int rr = 0; rr < 4; ++rr) {
    float* dst = gx + (size_t)(m0 + ty * 4 + rr) * G + n0;
#pragma unroll
    for (int cc = 0; cc < 8; ++cc) {
      int c = tx + 16 * cc;
      int g = n0 + c;
      float bias = bih[g] + (g < 512 ? bhh[g] : 0.0f);
      dst[c] = acc[rr][cc] + bias;
    }
  }
}

// ---------------------------------------------------------------------------
// Kernel C: MFMA word-GRU scan. 4 WGs x 512 threads (8 waves, 2/SIMD), each
// WG owns 16 utterances. Per step: gh[16][768] = h[16][256] @ Whh^T via
// 48 x mfma_f32_16x16x32_f16 per wave-set; wave w owns gate-dims
// [32w, 32w+32) for all three gates, so r/z/n for one (utt,dim) land in the
// SAME lane (C layout: col=lane&15 -> dim, row=quad*4+reg -> utt) and the
// GRU update runs entirely in registers. Whh B-fragments (192 f16 regs/lane)
// are loop-invariant MFMA operands -> AGPR-resident natively (no per-use
// moves, unlike the fdot2 structures of R1-R6). h (f16) lives in LDS in
// A-operand layout, double-buffered, 272-f16 row stride (optimal b128 bank
// spread); ONE LDS-only barrier per step; gx prefetched one step ahead.
// ---------------------------------------------------------------------------
__global__ __launch_bounds__(512)
__attribute__((amdgpu_waves_per_eu(2, 2)))
void gru_scan_mfma(const float* __restrict__ gx,    // [NUTT][L][G] w/ biases
                   const float* __restrict__ Whh,   // [G][D]
                   const float* __restrict__ bhh,   // [G]
                   _Float16* __restrict__ wo2) {    // [NUTT][L][D] f16
  __shared__ __align__(16) _Float16 hA[2][16 * 272];

  const int t = threadIdx.x;
  const int ub = blockIdx.x;          // utterances ub*16 .. ub*16+15
  const int w = t >> 6;               // wave 0..7
  const int lane = t & 63;
  const int quad = lane >> 4;
  const int col = lane & 15;

  // ---- B fragments: B[k][n], n = (2w+p)*16+col (+gate*256), k = kt*32+quad*8+j
  f16x8 Bf[3][2][8];
#pragma unroll
  for (int g3 = 0; g3 < 3; ++g3)
#pragma unroll
    for (int p = 0; p < 2; ++p)
#pragma unroll
      for (int kt = 0; kt < 8; ++kt) {
        const float* src = Whh +
            (size_t)(g3 * 256 + (2 * w + p) * 16 + col) * 256 + kt * 32 + quad * 8;
        float4 v0 = *(const float4*)(src);
        float4 v1 = *(const float4*)(src + 4);
        Bf[g3][p][kt] = f16x8{(_Float16)v0.x, (_Float16)v0.y, (_Float16)v0.z,
                              (_Float16)v0.w, (_Float16)v1.x, (_Float16)v1.y,
                              (_Float16)v1.z, (_Float16)v1.w};
      }

  // zero both h buffers (h0 = 0)
  for (int i = t; i < 2 * 16 * 272 / 2; i += 512) ((unsigned*)hA)[i] = 0u;

  const int dbase0 = (2 * w + 0) * 16 + col;
  const int dbase1 = (2 * w + 1) * 16 + col;
  const float bN0 = bhh[512 + dbase0];
  const float bN1 = bhh[512 + dbase1];

  unsigned rowOff[4];
#pragma unroll
  for (int i = 0; i < 4; ++i)
    rowOff[i] = (unsigned)((ub * 16 + quad * 4 + i) * 512) * 768u;

  float gc[3][2][4], gnx[3][2][4];
#pragma unroll
  for (int g3 = 0; g3 < 3; ++g3)
#pragma unroll
    for (int p = 0; p < 2; ++p) {
      const int doff = g3 * 256 + (p == 0 ? dbase0 : dbase1);
#pragma unroll
      for (int i = 0; i < 4; ++i)
        gc[g3][p][i] = gx[(size_t)rowOff[i] + doff];
    }

  float hprev[2][4] = {{0.f, 0.f, 0.f, 0.f}, {0.f, 0.f, 0.f, 0.f}};
  __syncthreads();

  auto step = [&](int ts, const _Float16* hc, _Float16* hnb,
                  float (&gcur)[3][2][4], float (&gnext)[3][2][4]) {
    // prefetch gx for t+1 (lands during this step's MFMA/update)
    const int tn = (ts + 1 < L) ? ts + 1 : ts;
#pragma unroll
    for (int g3 = 0; g3 < 3; ++g3)
#pragma unroll
      for (int p = 0; p < 2; ++p) {
        const int doff = g3 * 256 + (p == 0 ? dbase0 : dbase1) + tn * G;
#pragma unroll
        for (int i = 0; i < 4; ++i)
          gnext[g3][p][i] = gx[(size_t)rowOff[i] + doff];
      }
    // A fragments: A[m=col][k = kt*32 + quad*8 + j]
    f16x8 a[8];
#pragma unroll
    for (int kt = 0; kt < 8; ++kt)
      a[kt] = *(const f16x8*)(hc + col * 272 + kt * 32 + quad * 8);
    // MFMA: 6 independent 8-deep K-chains
    f32x4 acc[3][2];
#pragma unroll
    for (int g3 = 0; g3 < 3; ++g3)
#pragma unroll
      for (int p = 0; p < 2; ++p) {
        f32x4 c = {0.f, 0.f, 0.f, 0.f};
#pragma unroll
        for (int kt = 0; kt < 8; ++kt)
          c = __builtin_amdgcn_mfma_f32_16x16x32_f16(a[kt], Bf[g3][p][kt], c,
                                                     0, 0, 0);
        acc[g3][p] = c;
      }
    // update: lane owns (m = quad*4+i, d = (2w+p)*16+col), all 8 slots valid
#pragma unroll
    for (int p = 0; p < 2; ++p) {
      const int d = (p == 0) ? dbase0 : dbase1;
      const float bN = (p == 0) ? bN0 : bN1;
#pragma unroll
      for (int i = 0; i < 4; ++i) {
        float rr = sigm(gcur[0][p][i] + acc[0][p][i]);
        float zz = sigm(gcur[1][p][i] + acc[1][p][i]);
        float nn = tanh_f(gcur[2][p][i] + rr * (acc[2][p][i] + bN));
        float hv = fmaf(zz, hprev[p][i] - nn, nn);   // (1-z)*n + z*h
        hprev[p][i] = hv;
        const int m = quad * 4 + i;
        wo2[((size_t)(ub * 16 + m) * L + ts) * D + d] = (_Float16)hv;
        hnb[m * 272 + d] = (_Float16)hv;
      }
    }
    lds_barrier();
  };

  for (int ts = 0; ts < L; ts += 2) {
    step(ts, hA[0], hA[1], gc, gnx);
    step(ts + 1, hA[1], hA[0], gnx, gc);
  }
}

// ---------------------------------------------------------------------------
// Kernel D: attention pool over word_out (f16) -> utt[64][256] (f32)
// ---------------------------------------------------------------------------
__global__ __launch_bounds__(256) void attn_pool_word(
    const _Float16* __restrict__ wo2, const float* __restrict__ uaw,
    float* __restrict__ utt) {
  __shared__ float wsh[D];
  __shared__ float lg[L];
  __shared__ float red[8];
  const int tid = threadIdx.x, b = blockIdx.x;
  wsh[tid] = uaw[tid];
  __syncthreads();

  const int wid = tid >> 6, lane = tid & 63;
  const _Float16* base = wo2 + (size_t)b * L * D;
  for (int t = wid; t < L; t += 4) {
    const _Float16* row = base + (size_t)t * D;
    float p = 0.0f;
#pragma unroll
    for (int j = 0; j < 4; ++j)
      p = fmaf((float)row[lane + 64 * j], wsh[lane + 64 * j], p);
#pragma unroll
    for (int off = 32; off; off >>= 1) p += __shfl_down(p, off);
    if (lane == 0) lg[t] = p;                  // ua_b cancels in softmax
  }
  __syncthreads();

  float m = fmaxf(lg[tid], lg[tid + 256]);
#pragma unroll
  for (int off = 32; off; off >>= 1) m = fmaxf(m, __shfl_down(m, off));
  if (lane == 0) red[wid] = m;
  __syncthreads();
  m = fmaxf(fmaxf(red[0], red[1]), fmaxf(red[2], red[3]));

  float e0 = __expf(lg[tid] - m), e1 = __expf(lg[tid + 256] - m);
  float s = e0 + e1;
#pragma unroll
  for (int off = 32; off; off >>= 1) s += __shfl_down(s, off);
  if (lane == 0) red[4 + wid] = s;
  __syncthreads();
  s = red[4] + red[5] + red[6] + red[7];
  float inv = 1.0f / s;
  lg[tid] = e0 * inv;
  lg[tid + 256] = e1 * inv;
  __syncthreads();

  float acc = 0.0f;
#pragma unroll 4
  for (int t = 0; t < L; ++t)
    acc = fmaf(lg[t], (float)base[(size_t)t * D + tid], acc);
  utt[(size_t)b * D + tid] = acc;
}

// ---------------------------------------------------------------------------
// Kernel E: sentence GRU (T=1, h0=0) -> dialog_vec = (1-z)*n
// ---------------------------------------------------------------------------
__global__ __launch_bounds__(256) void sent_kernel(
    const float* __restrict__ utt, const float* __restrict__ Wih,
    const float* __restrict__ bih, const float* __restrict__ bhh,
    float* __restrict__ out) {
  __shared__ float u[D];
  const int d = threadIdx.x, b = blockIdx.x;
  u[d] = utt[(size_t)b * D + d];
  __syncthreads();

  const float* wr = Wih + (size_t)d * D;
  const float* wz = Wih + (size_t)(D + d) * D;
  const float* wn = Wih + (size_t)(2 * D + d) * D;
  float ar = 0.0f, az = 0.0f, an = 0.0f;
  for (int k = 0; k < D; k += 4) {
    float4 vr = *(const float4*)(wr + k);
    float4 vz = *(const float4*)(wz + k);
    float4 vn = *(const float4*)(wn + k);
    float u0 = u[k], u1 = u[k + 1], u2 = u[k + 2], u3 = u[k + 3];
    ar += vr.x * u0 + vr.y * u1 + vr.z * u2 + vr.w * u3;
    az += vz.x * u0 + vz.y * u1 + vz.z * u2 + vz.w * u3;
    an += vn.x * u0 + vn.y * u1 + vn.z * u2 + vn.w * u3;
  }
  float xr = ar + bih[d];
  float xz = az + bih[D + d];
  float xn = an + bih[2 * D + d];
  float r = sigm(xr + bhh[d]);
  float z = sigm(xz + bhh[D + d]);
  float n = tanh_f(xn + r * bhh[2 * D + d]);
  out[(size_t)b * D + d] = (1.0f - z) * n;
}

// ---------------------------------------------------------------------------
extern "C" void kernel_launch(void* const* d_in, const int* in_sizes, int n_in,
                              void* d_out, int out_size, void* d_ws, size_t ws_size,
                              hipStream_t stream) {
  const int* tokens    = (const int*)d_in[0];
  const float* embed   = (const float*)d_in[1];
  const float* wg_Wih  = (const float*)d_in[2];
  const float* wg_Whh  = (const float*)d_in[3];
  const float* wg_bih  = (const float*)d_in[4];
  const float* wg_bhh  = (const float*)d_in[5];
  const float* ua_w    = (const float*)d_in[6];
  // d_in[7] ua_b: softmax shift-invariant -> unused
  const float* sg_Wih  = (const float*)d_in[8];
  // d_in[9] sg_Whh: h0 == 0 -> unused
  const float* sg_bih  = (const float*)d_in[10];
  const float* sg_bhh  = (const float*)d_in[11];
  // d_in[12..13] da_w/da_b: softmax over T=1 -> unused
  float* out = (float*)d_out;

  char* ws = (char*)d_ws;
  float*     gx  = (float*)ws;                                   // 96 MB
  _Float16*  wo2 = (_Float16*)(ws + (size_t)NUTT * L * G * 4);   // 16 MB
  float*     utt = (float*)(ws + (size_t)NUTT * L * G * 4
                               + (size_t)NUTT * L * D * 2);      // 64 KB

  dim3 gB(512, 6);
  gx_gemm<<<gB, 256, 0, stream>>>(tokens, embed, wg_Wih, wg_bih, wg_bhh, gx);
  gru_scan_mfma<<<4, 512, 0, stream>>>(gx, wg_Whh, wg_bhh, wo2);
  attn_pool_word<<<NUTT, 256, 0, stream>>>(wo2, ua_w, utt);
  sent_kernel<<<NUTT, 256, 0, stream>>>(utt, sg_Wih, sg_bih, sg_bhh, out);
}

// Round 8
// 1676.074 us; speedup vs baseline: 2.1091x; 2.1091x over previous
//
#include <hip/hip_runtime.h>

typedef _Float16 half2_t __attribute__((ext_vector_type(2)));

constexpr int D = 256;
constexpr int NUTT = 64;
constexpr int L = 512;
constexpr int G = 768;           // 3*D

__device__ __forceinline__ half2_t u2h(unsigned int u) {
  return __builtin_bit_cast(half2_t, u);
}
__device__ __forceinline__ unsigned int pack2(float a, float b) {
  half2_t h{(_Float16)a, (_Float16)b};
  return __builtin_bit_cast(unsigned int, h);
}

__device__ __forceinline__ float fdot2(half2_t a, half2_t b, float c) {
#if defined(__has_builtin)
#if __has_builtin(__builtin_amdgcn_fdot2)
  return __builtin_amdgcn_fdot2(a, b, c, false);
#else
  return c + (float)a.x * (float)b.x + (float)a.y * (float)b.y;
#endif
#else
  return c + (float)a.x * (float)b.x + (float)a.y * (float)b.y;
#endif
}

// LDS-only barrier: orders ds_* ops across the workgroup WITHOUT draining
// vmcnt — global loads/stores stay in flight across steps.
__device__ __forceinline__ void lds_barrier() {
  asm volatile("s_waitcnt lgkmcnt(0)\n\ts_barrier" ::: "memory");
}

__device__ __forceinline__ float sigm(float x) {
  return 1.0f / (1.0f + __expf(-x));
}
__device__ __forceinline__ float tanh_f(float x) {
  float e = __expf(2.0f * x);
  return 1.0f - 2.0f / (1.0f + e);
}

// ---------------------------------------------------------------------------
// Kernel B: gx[m][g] = embed[tokens[m]][:] . Wih[g][:] + bih[g] (+bhh[g] for
// the r/z gates g<512 — folded so the scan kernel saves registers).
// ---------------------------------------------------------------------------
__global__ __launch_bounds__(256) void gx_gemm(
    const int* __restrict__ tokens, const float* __restrict__ embed,
    const float* __restrict__ Wih, const float* __restrict__ bih,
    const float* __restrict__ bhh, float* __restrict__ gx) {
  __shared__ float As[64][33];
  __shared__ float Bs[32][129];
  __shared__ int toks[64];

  const int tid = threadIdx.x;
  const int m0 = blockIdx.x * 64;
  const int n0 = blockIdx.y * 128;
  if (tid < 64) toks[tid] = tokens[m0 + tid];
  __syncthreads();

  const int ty = tid >> 4;
  const int tx = tid & 15;
  float acc[4][8] = {};

  for (int k0 = 0; k0 < 256; k0 += 32) {
    {
      const int i = tid >> 2;
      const int kq = (tid & 3) * 4;
      const float* src = embed + (size_t)toks[i] * D + k0;
      float4 v0 = *(const float4*)(src + kq);
      float4 v1 = *(const float4*)(src + kq + 16);
      As[i][kq + 0] = v0.x; As[i][kq + 1] = v0.y;
      As[i][kq + 2] = v0.z; As[i][kq + 3] = v0.w;
      As[i][kq + 16] = v1.x; As[i][kq + 17] = v1.y;
      As[i][kq + 18] = v1.z; As[i][kq + 19] = v1.w;
    }
    {
      const int goff = tid >> 3;
      const int kq = (tid & 7) * 4;
      for (int gp = 0; gp < 128; gp += 32) {
        const float* src = Wih + (size_t)(n0 + goff + gp) * D + k0 + kq;
        float4 v = *(const float4*)src;
        Bs[kq + 0][goff + gp] = v.x;
        Bs[kq + 1][goff + gp] = v.y;
        Bs[kq + 2][goff + gp] = v.z;
        Bs[kq + 3][goff + gp] = v.w;
      }
    }
    __syncthreads();
    const int r0 = ty * 4;
#pragma unroll 4
    for (int k = 0; k < 32; ++k) {
      float a0 = As[r0 + 0][k], a1 = As[r0 + 1][k];
      float a2 = As[r0 + 2][k], a3 = As[r0 + 3][k];
#pragma unroll
      for (int cc = 0; cc < 8; ++cc) {
        float bv = Bs[k][tx + 16 * cc];
        acc[0][cc] = fmaf(a0, bv, acc[0][cc]);
        acc[1][cc] = fmaf(a1, bv, acc[1][cc]);
        acc[2][cc] = fmaf(a2, bv, acc[2][cc]);
        acc[3][cc] = fmaf(a3, bv, acc[3][cc]);
      }
    }
    __syncthreads();
  }
#pragma unroll
  for (int rr = 0; rr < 4; ++rr) {
    float* dst = gx + (size_t)(m0 + ty * 4 + rr) * G + n0;
#pragma unroll
    for (int cc = 0; cc < 8; ++cc) {
      int c = tx + 16 * cc;
      int g = n0 + c;
      float bias = bih[g] + (g < 512 ? bhh[g] : 0.0f);
      dst[c] = acc[rr][cc] + bias;
    }
  }
}

// ---------------------------------------------------------------------------
// Kernel C: persistent word-GRU scan. 64 WGs x 1024 threads, waves_per_eu(4,4)
// pins exactly 4 waves/SIMD (128 unified regs/wave; forbids the RA's 64-reg
// 2-WG-co-residency target that sank R5).
// Thread t: p = t>>3 (d-pair: dims 2p,2p+1), ke = t&7 (K-eighth).
// Weights: 6 row-slices (3 gates x 2 dims) x 16 half2 = 96 VGPRs — the first
// layout where weights + working set fit the 128-reg class (invariant:
// weights/thread = 384KB/nthreads; LDS h-traffic /= rows-per-read=6).
// h (f16) double-buffered in LDS, 8 chunks of 64B at 80-B stride: the 8
// simultaneous b128 addresses hit bank-quads {0,20,8,28,16,4,24,12} — fully
// disjoint, conflict-free; 8-lane same-address groups broadcast for free.
// Partials combined with 3x __shfl_xor (1,2,4 — in-wave); redundant update
// on all 8 partners; gx loaded IN-step (consumed ~900cy later -> L3 latency
// hidden, no prefetch registers). ONE LDS-only barrier per step.
// ---------------------------------------------------------------------------
__global__ __launch_bounds__(1024)
__attribute__((amdgpu_waves_per_eu(4, 4)))
void gru_scan_word(
    const float* __restrict__ gx,    // [NUTT][L][G] (w/ b_ih, + bhh r/z)
    const float* __restrict__ Whh,   // [G][D]
    const float* __restrict__ bhh,   // [G]
    _Float16* __restrict__ wo2) {    // [NUTT][L][D] f16
  __shared__ __align__(16) unsigned char hb[2][8 * 80];  // 640 B x2

  const int t = threadIdx.x;
  const int b = blockIdx.x;
  const int p = t >> 3;              // 0..127 : dims {2p, 2p+1}
  const int ke = t & 7;              // K-eighth: k in [ke*32, ke*32+32)

  // --- weights: rows g*256 + {2p,2p+1}, k-slice [ke*32, ke*32+32) ---
  half2_t wgt[6][16];
#pragma unroll
  for (int g3 = 0; g3 < 3; ++g3)
#pragma unroll
    for (int dd = 0; dd < 2; ++dd) {
      const float* src = Whh + (size_t)(g3 * 256 + 2 * p + dd) * D + ke * 32;
      half2_t* wj = wgt[g3 * 2 + dd];
#pragma unroll
      for (int c = 0; c < 8; ++c) {
        float4 v = *(const float4*)(src + 4 * c);
        wj[2 * c]     = half2_t{(_Float16)v.x, (_Float16)v.y};
        wj[2 * c + 1] = half2_t{(_Float16)v.z, (_Float16)v.w};
      }
    }

  const float bN0 = bhh[512 + 2 * p];
  const float bN1 = bhh[512 + 2 * p + 1];
  const float* gxb = gx + (size_t)b * L * G + 2 * p;
  _Float16* wob = wo2 + (size_t)b * L * D + 2 * p;

  // zero both h buffers (h0 = 0): 2*640 B = 320 dwords
  if (t < 320) ((unsigned*)hb)[t] = 0u;
  float hprev0 = 0.0f, hprev1 = 0.0f;
  __syncthreads();

  const unsigned char* hrd[2] = {hb[0] + ke * 80, hb[1] + ke * 80};
  // writer slot for dims {2p,2p+1}: chunk p>>4, dword p&15
  unsigned char* hwr[2] = {hb[0] + (p >> 4) * 80 + (p & 15) * 4,
                           hb[1] + (p >> 4) * 80 + (p & 15) * 4};

  for (int ts = 0; ts < L; ++ts) {
    const int cur = ts & 1;
    // in-step gx load — consumed after ~900cy of dot2/shfl, latency hidden
    const float* gp = gxb + (size_t)ts * G;
    float2 grv = *(const float2*)(gp);
    float2 gzv = *(const float2*)(gp + 256);
    float2 gnv = *(const float2*)(gp + 512);

    const uint4* hc = (const uint4*)hrd[cur];
    float a0 = 0.f, a1 = 0.f, a2 = 0.f, a3 = 0.f, a4 = 0.f, a5 = 0.f;
    // first half of the chunk (2 b128), then second — caps h-transients at 8
#pragma unroll
    for (int half = 0; half < 2; ++half) {
      uint4 v0 = hc[2 * half];
      uint4 v1 = hc[2 * half + 1];
      unsigned hw[8] = {v0.x, v0.y, v0.z, v0.w, v1.x, v1.y, v1.z, v1.w};
#pragma unroll
      for (int c = 0; c < 8; ++c) {
        const int wc = half * 8 + c;
        half2_t hh = u2h(hw[c]);
        a0 = fdot2(wgt[0][wc], hh, a0);
        a1 = fdot2(wgt[1][wc], hh, a1);
        a2 = fdot2(wgt[2][wc], hh, a2);
        a3 = fdot2(wgt[3][wc], hh, a3);
        a4 = fdot2(wgt[4][wc], hh, a4);
        a5 = fdot2(wgt[5][wc], hh, a5);
      }
    }
    // combine over the 8 K-eighths (lanes t^1, t^2, t^4 — same wave)
#pragma unroll
    for (int lvl = 1; lvl <= 4; lvl <<= 1) {
      a0 += __shfl_xor(a0, lvl, 64);
      a1 += __shfl_xor(a1, lvl, 64);
      a2 += __shfl_xor(a2, lvl, 64);
      a3 += __shfl_xor(a3, lvl, 64);
      a4 += __shfl_xor(a4, lvl, 64);
      a5 += __shfl_xor(a5, lvl, 64);
    }

    // redundant update on all 8 partners (identical fp -> identical result)
    float r0 = sigm(grv.x + a0);
    float r1 = sigm(grv.y + a1);
    float z0 = sigm(gzv.x + a2);
    float z1 = sigm(gzv.y + a3);
    float n0 = tanh_f(gnv.x + r0 * (a4 + bN0));
    float n1 = tanh_f(gnv.y + r1 * (a5 + bN1));
    float h0 = fmaf(z0, hprev0 - n0, n0);      // (1-z)*n + z*h
    float h1 = fmaf(z1, hprev1 - n1, n1);
    hprev0 = h0; hprev1 = h1;
    if (ke == 0) {
      unsigned hp = pack2(h0, h1);
      *(unsigned*)hwr[cur ^ 1] = hp;
      *(unsigned*)(wob + (size_t)ts * D) = hp;   // f16 pair, coalesced
    }
    lds_barrier();
  }
}

// ---------------------------------------------------------------------------
// Kernel D: attention pool over word_out (f16) -> utt[64][256] (f32)
// ---------------------------------------------------------------------------
__global__ __launch_bounds__(256) void attn_pool_word(
    const _Float16* __restrict__ wo2, const float* __restrict__ uaw,
    float* __restrict__ utt) {
  __shared__ float wsh[D];
  __shared__ float lg[L];
  __shared__ float red[8];
  const int tid = threadIdx.x, b = blockIdx.x;
  wsh[tid] = uaw[tid];
  __syncthreads();

  const int wid = tid >> 6, lane = tid & 63;
  const _Float16* base = wo2 + (size_t)b * L * D;
  for (int t = wid; t < L; t += 4) {
    const _Float16* row = base + (size_t)t * D;
    float p = 0.0f;
#pragma unroll
    for (int j = 0; j < 4; ++j)
      p = fmaf((float)row[lane + 64 * j], wsh[lane + 64 * j], p);
#pragma unroll
    for (int off = 32; off; off >>= 1) p += __shfl_down(p, off);
    if (lane == 0) lg[t] = p;                  // ua_b cancels in softmax
  }
  __syncthreads();

  float m = fmaxf(lg[tid], lg[tid + 256]);
#pragma unroll
  for (int off = 32; off; off >>= 1) m = fmaxf(m, __shfl_down(m, off));
  if (lane == 0) red[wid] = m;
  __syncthreads();
  m = fmaxf(fmaxf(red[0], red[1]), fmaxf(red[2], red[3]));

  float e0 = __expf(lg[tid] - m), e1 = __expf(lg[tid + 256] - m);
  float s = e0 + e1;
#pragma unroll
  for (int off = 32; off; off >>= 1) s += __shfl_down(s, off);
  if (lane == 0) red[4 + wid] = s;
  __syncthreads();
  s = red[4] + red[5] + red[6] + red[7];
  float inv = 1.0f / s;
  lg[tid] = e0 * inv;
  lg[tid + 256] = e1 * inv;
  __syncthreads();

  float acc = 0.0f;
#pragma unroll 4
  for (int t = 0; t < L; ++t)
    acc = fmaf(lg[t], (float)base[(size_t)t * D + tid], acc);
  utt[(size_t)b * D + tid] = acc;
}

// ---------------------------------------------------------------------------
// Kernel E: sentence GRU (T=1, h0=0) -> dialog_vec = (1-z)*n
// ---------------------------------------------------------------------------
__global__ __launch_bounds__(256) void sent_kernel(
    const float* __restrict__ utt, const float* __restrict__ Wih,
    const float* __restrict__ bih, const float* __restrict__ bhh,
    float* __restrict__ out) {
  __shared__ float u[D];
  const int d = threadIdx.x, b = blockIdx.x;
  u[d] = utt[(size_t)b * D + d];
  __syncthreads();

  const float* wr = Wih + (size_t)d * D;
  const float* wz = Wih + (size_t)(D + d) * D;
  const float* wn = Wih + (size_t)(2 * D + d) * D;
  float ar = 0.0f, az = 0.0f, an = 0.0f;
  for (int k = 0; k < D; k += 4) {
    float4 vr = *(const float4*)(wr + k);
    float4 vz = *(const float4*)(wz + k);
    float4 vn = *(const float4*)(wn + k);
    float u0 = u[k], u1 = u[k + 1], u2 = u[k + 2], u3 = u[k + 3];
    ar += vr.x * u0 + vr.y * u1 + vr.z * u2 + vr.w * u3;
    az += vz.x * u0 + vz.y * u1 + vz.z * u2 + vz.w * u3;
    an += vn.x * u0 + vn.y * u1 + vn.z * u2 + vn.w * u3;
  }
  float xr = ar + bih[d];
  float xz = az + bih[D + d];
  float xn = an + bih[2 * D + d];
  float r = sigm(xr + bhh[d]);
  float z = sigm(xz + bhh[D + d]);
  float n = tanh_f(xn + r * bhh[2 * D + d]);
  out[(size_t)b * D + d] = (1.0f - z) * n;
}

// ---------------------------------------------------------------------------
extern "C" void kernel_launch(void* const* d_in, const int* in_sizes, int n_in,
                              void* d_out, int out_size, void* d_ws, size_t ws_size,
                              hipStream_t stream) {
  const int* tokens    = (const int*)d_in[0];
  const float* embed   = (const float*)d_in[1];
  const float* wg_Wih  = (const float*)d_in[2];
  const float* wg_Whh  = (const float*)d_in[3];
  const float* wg_bih  = (const float*)d_in[4];
  const float* wg_bhh  = (const float*)d_in[5];
  const float* ua_w    = (const float*)d_in[6];
  // d_in[7] ua_b: softmax shift-invariant -> unused
  const float* sg_Wih  = (const float*)d_in[8];
  // d_in[9] sg_Whh: h0 == 0 -> unused
  const float* sg_bih  = (const float*)d_in[10];
  const float* sg_bhh  = (const float*)d_in[11];
  // d_in[12..13] da_w/da_b: softmax over T=1 -> unused
  float* out = (float*)d_out;

  char* ws = (char*)d_ws;
  float*     gx  = (float*)ws;                                   // 96 MB
  _Float16*  wo2 = (_Float16*)(ws + (size_t)NUTT * L * G * 4);   // 16 MB
  float*     utt = (float*)(ws + (size_t)NUTT * L * G * 4
                               + (size_t)NUTT * L * D * 2);      // 64 KB

  dim3 gB(512, 6);
  gx_gemm<<<gB, 256, 0, stream>>>(tokens, embed, wg_Wih, wg_bih, wg_bhh, gx);
  gru_scan_word<<<NUTT, 1024, 0, stream>>>(gx, wg_Whh, wg_bhh, wo2);
  attn_pool_word<<<NUTT, 256, 0, stream>>>(wo2, ua_w, utt);
  sent_kernel<<<NUTT, 256, 0, stream>>>(utt, sg_Wih, sg_bih, sg_bhh, out);
}